// Round 2
// baseline (5809.653 us; speedup 1.0000x reference)
//
#include <hip/hip_runtime.h>

// TemporalDetector: 2-layer LSTM (B=16384, T=64, I=64, H=32) + variance vote head.
// Layout: 256 blocks x 1024 threads. lane (0..63) = batch element within block,
// wave (0..15) = 2 hidden dims (d0=2w, d1=2w+1) x 4 gate types (8 gate rows).
// Weights are wave-uniform (readfirstlane) -> s_load + v_fmac with SGPR operand.
// h0/h1 state in LDS (stride 34: 2-way bank alias = free). x staged per 4-step
// tile into LDS with chunk-XOR swizzle for conflict-free ds_read_b128.

#define H_STRIDE 34
#define H_BUF    (64 * H_STRIDE)

__device__ __forceinline__ float frcp(float v) { return __builtin_amdgcn_rcpf(v); }
__device__ __forceinline__ float sigf(float v) { return frcp(1.0f + __expf(-v)); }
__device__ __forceinline__ float tanh_(float v) { return 2.0f * frcp(1.0f + __expf(-2.0f * v)) - 1.0f; }

// layer-0 input-proj FMA bundle: 8 gate rows (i,f,g,o) x (d0,d1), K over I=64
#define XF(xe, ii) { const float _x = (xe); \
  a0 += _x * wih0[(d0     ) * 64 + (ii)]; a1 += _x * wih0[(d1     ) * 64 + (ii)]; \
  a2 += _x * wih0[(32 + d0) * 64 + (ii)]; a3 += _x * wih0[(32 + d1) * 64 + (ii)]; \
  a4 += _x * wih0[(64 + d0) * 64 + (ii)]; a5 += _x * wih0[(64 + d1) * 64 + (ii)]; \
  a6 += _x * wih0[(96 + d0) * 64 + (ii)]; a7 += _x * wih0[(96 + d1) * 64 + (ii)]; }

// layer-0 recurrent FMA bundle: K over H=32
#define HF(he, jj) { const float _h = (he); \
  a0 += _h * whh0[(d0     ) * 32 + (jj)]; a1 += _h * whh0[(d1     ) * 32 + (jj)]; \
  a2 += _h * whh0[(32 + d0) * 32 + (jj)]; a3 += _h * whh0[(32 + d1) * 32 + (jj)]; \
  a4 += _h * whh0[(64 + d0) * 32 + (jj)]; a5 += _h * whh0[(64 + d1) * 32 + (jj)]; \
  a6 += _h * whh0[(96 + d0) * 32 + (jj)]; a7 += _h * whh0[(96 + d1) * 32 + (jj)]; }

// layer-1 input(av from h0-new) + recurrent(bv from h1-old) bundle
#define ZF(ae, be, jj) { const float _a = (ae), _b = (be); \
  z0 += _a * wih1[(d0     ) * 32 + (jj)]; z0 += _b * whh1[(d0     ) * 32 + (jj)]; \
  z1 += _a * wih1[(d1     ) * 32 + (jj)]; z1 += _b * whh1[(d1     ) * 32 + (jj)]; \
  z2 += _a * wih1[(32 + d0) * 32 + (jj)]; z2 += _b * whh1[(32 + d0) * 32 + (jj)]; \
  z3 += _a * wih1[(32 + d1) * 32 + (jj)]; z3 += _b * whh1[(32 + d1) * 32 + (jj)]; \
  z4 += _a * wih1[(64 + d0) * 32 + (jj)]; z4 += _b * whh1[(64 + d0) * 32 + (jj)]; \
  z5 += _a * wih1[(64 + d1) * 32 + (jj)]; z5 += _b * whh1[(64 + d1) * 32 + (jj)]; \
  z6 += _a * wih1[(96 + d0) * 32 + (jj)]; z6 += _b * whh1[(96 + d0) * 32 + (jj)]; \
  z7 += _a * wih1[(96 + d1) * 32 + (jj)]; z7 += _b * whh1[(96 + d1) * 32 + (jj)]; }

__global__ void __launch_bounds__(1024, 4)
lstm_fused(const float* __restrict__ x,
           const float* __restrict__ wih0, const float* __restrict__ whh0,
           const float* __restrict__ bih0, const float* __restrict__ bhh0,
           const float* __restrict__ wih1, const float* __restrict__ whh1,
           const float* __restrict__ bih1, const float* __restrict__ bhh1,
           float* __restrict__ out, float* __restrict__ red)
{
    __shared__ float xs[64 * 256];     // [b][chunk-swizzled 4*64 floats] = 64KB
    __shared__ float h0s[2 * H_BUF];   // double-buffered layer-0 h
    __shared__ float h1s[H_BUF];       // layer-1 h (in-place, barrier-protected)

    const int tid  = threadIdx.x;
    const int lane = tid & 63;                                  // batch-local index
    const int wid  = __builtin_amdgcn_readfirstlane(tid >> 6);  // wave id, SGPR
    const int b0   = blockIdx.x << 6;

    for (int k = tid; k < H_BUF; k += 1024) { h0s[k] = 0.0f; h1s[k] = 0.0f; }

    const int d0 = wid * 2, d1 = d0 + 1;

    // hoisted biases (wave-uniform -> SGPRs)
    const float bi0 = bih0[d0]      + bhh0[d0],      bi1 = bih0[d1]      + bhh0[d1];
    const float bf0 = bih0[32 + d0] + bhh0[32 + d0], bf1 = bih0[32 + d1] + bhh0[32 + d1];
    const float bg0 = bih0[64 + d0] + bhh0[64 + d0], bg1 = bih0[64 + d1] + bhh0[64 + d1];
    const float bo0 = bih0[96 + d0] + bhh0[96 + d0], bo1 = bih0[96 + d1] + bhh0[96 + d1];
    const float ci0 = bih1[d0]      + bhh1[d0],      ci1 = bih1[d1]      + bhh1[d1];
    const float cf0 = bih1[32 + d0] + bhh1[32 + d0], cf1 = bih1[32 + d1] + bhh1[32 + d1];
    const float cg0 = bih1[64 + d0] + bhh1[64 + d0], cg1 = bih1[64 + d1] + bhh1[64 + d1];
    const float co0 = bih1[96 + d0] + bhh1[96 + d0], co1 = bih1[96 + d1] + bhh1[96 + d1];

    float c0a = 0.f, c0b = 0.f, c1a = 0.f, c1b = 0.f, vs = 0.f, vq = 0.f;
    int p = 0;

    for (int t0 = 0; t0 < 64; t0 += 4) {
        // ---- stage x tile: x[b, i, t0..t0+3] for all 64 b, 64 i ----
        #pragma unroll
        for (int k = 0; k < 4; ++k) {
            const int bl = k * 16 + wid;
            const float4 v = *(const float4*)(x + (((size_t)(b0 + bl)) << 12) + (lane << 6) + t0);
            const int base = bl << 8;
            const int ci = lane >> 2, e = lane & 3;
            xs[base + (((0  + ci) ^ bl) << 2) + e] = v.x;
            xs[base + (((16 + ci) ^ bl) << 2) + e] = v.y;
            xs[base + (((32 + ci) ^ bl) << 2) + e] = v.z;
            xs[base + (((48 + ci) ^ bl) << 2) + e] = v.w;
        }
        __syncthreads();

        #pragma unroll 1
        for (int tt = 0; tt < 4; ++tt) {
            const int t = t0 + tt;

            // ---------- layer 0 ----------
            float a0 = bi0, a1 = bi1, a2 = bf0, a3 = bf1;
            float a4 = bg0, a5 = bg1, a6 = bo0, a7 = bo1;

            const int xbase = lane << 8;
            #pragma unroll
            for (int cq = 0; cq < 16; ++cq) {
                const int c = tt * 16 + cq;
                const float4 xv = *(const float4*)&xs[xbase + ((c ^ lane) << 2)];
                const int i = cq << 2;
                XF(xv.x, i) XF(xv.y, i + 1) XF(xv.z, i + 2) XF(xv.w, i + 3)
            }
            const float* h0r = &h0s[p * H_BUF + lane * H_STRIDE];
            #pragma unroll
            for (int j = 0; j < 32; j += 2) {
                const float2 hv = *(const float2*)&h0r[j];
                HF(hv.x, j) HF(hv.y, j + 1)
            }
            const float si = sigf(a0), si2 = sigf(a1);
            const float sf = sigf(a2), sf2 = sigf(a3);
            const float tg = tanh_(a4), tg2 = tanh_(a5);
            const float so = sigf(a6), so2 = sigf(a7);
            c0a = sf  * c0a + si  * tg;   const float hn0 = so  * tanh_(c0a);
            c0b = sf2 * c0b + si2 * tg2;  const float hn1 = so2 * tanh_(c0b);
            float* h0w = &h0s[(p ^ 1) * H_BUF + lane * H_STRIDE];
            *(float2*)&h0w[d0] = make_float2(hn0, hn1);
            __syncthreads();   // h0-new visible to all waves

            // ---------- layer 1 ----------
            float z0 = ci0, z1 = ci1, z2 = cf0, z3 = cf1;
            float z4 = cg0, z5 = cg1, z6 = co0, z7 = co1;
            const float* h0n = &h0s[(p ^ 1) * H_BUF + lane * H_STRIDE];
            const float* h1r = &h1s[lane * H_STRIDE];
            #pragma unroll
            for (int j = 0; j < 32; j += 2) {
                const float2 av = *(const float2*)&h0n[j];
                const float2 bv = *(const float2*)&h1r[j];
                ZF(av.x, bv.x, j) ZF(av.y, bv.y, j + 1)
            }
            __syncthreads();   // all h1-old reads done before in-place write

            const float yi = sigf(z0), yi2 = sigf(z1);
            const float yf = sigf(z2), yf2 = sigf(z3);
            const float yg = tanh_(z4), yg2 = tanh_(z5);
            const float yo = sigf(z6), yo2 = sigf(z7);
            c1a = yf  * c1a + yi  * yg;   const float ho0 = yo  * tanh_(c1a);
            c1b = yf2 * c1b + yi2 * yg2;  const float ho1 = yo2 * tanh_(c1b);
            float* h1w = &h1s[lane * H_STRIDE];
            *(float2*)&h1w[d0] = make_float2(ho0, ho1);

            *(float2*)(out + (((size_t)(b0 + lane)) << 11) + (t << 5) + d0) = make_float2(ho0, ho1);
            vs += ho0 + ho1;
            vq += ho0 * ho0 + ho1 * ho1;
            p ^= 1;
        }
    }

    // variance partials: wave reduce then one atomic pair per wave
    #pragma unroll
    for (int off = 32; off > 0; off >>= 1) {
        vs += __shfl_down(vs, off);
        vq += __shfl_down(vq, off);
    }
    if (lane == 0) {
        atomicAdd(&red[0], vs);
        atomicAdd(&red[1], vq);
    }
}

__global__ void zero_red(float* red)
{
    if (threadIdx.x < 2) red[threadIdx.x] = 0.0f;
}

__global__ void finalize(const float* __restrict__ red, float* __restrict__ out)
{
    const double N = 33554432.0;   // 16384*64*32
    const double s = (double)red[0];
    const double q = (double)red[1];
    const double var = (q - s * s / N) / (N - 1.0);
    const float score = 1.0f / (1.0f + __expf(-5.0f * (float)var));
    out[33554432] = score;
    out[33554433] = 1.0f - score;
}

extern "C" void kernel_launch(void* const* d_in, const int* in_sizes, int n_in,
                              void* d_out, int out_size, void* d_ws, size_t ws_size,
                              hipStream_t stream)
{
    const float* x    = (const float*)d_in[0];
    const float* wih0 = (const float*)d_in[1];
    const float* whh0 = (const float*)d_in[2];
    const float* bih0 = (const float*)d_in[3];
    const float* bhh0 = (const float*)d_in[4];
    const float* wih1 = (const float*)d_in[5];
    const float* whh1 = (const float*)d_in[6];
    const float* bih1 = (const float*)d_in[7];
    const float* bhh1 = (const float*)d_in[8];
    float* out = (float*)d_out;
    float* red = (float*)d_ws;   // red[0]=sum, red[1]=sumsq (ws is re-poisoned; zero first)

    hipLaunchKernelGGL(zero_red, dim3(1), dim3(64), 0, stream, red);
    hipLaunchKernelGGL(lstm_fused, dim3(256), dim3(1024), 0, stream,
                       x, wih0, whh0, bih0, bhh0, wih1, whh1, bih1, bhh1, out, red);
    hipLaunchKernelGGL(finalize, dim3(1), dim3(1), 0, stream, red, out);
}

// Round 4
// 1405.254 us; speedup vs baseline: 4.1342x; 4.1342x over previous
//
#include <hip/hip_runtime.h>

// TemporalDetector: 2-layer LSTM (B=16384, T=64, I=64, H=32) + variance vote head.
// R3 change: ALL weights staged to LDS (80 KB) -> per-FMA weight operand is a
// wave-uniform-address ds_read_b128 (LDS broadcast), eliminating the per-step
// uniform-global weight refetch that dominated R2 (5577 us, 17x VALU inflation).
// x tile stored bf16 (32 KB) to fit LDS budget: 32K xs + 80K w + 27K h = 139 KB.

#define HS 36              // h row stride (floats): 144 B = 16B-aligned, conflict-free phases
#define HB (64 * HS)

__device__ __forceinline__ float frcp(float v) { return __builtin_amdgcn_rcpf(v); }
__device__ __forceinline__ float sigf(float v) { return frcp(1.0f + __expf(-v)); }
__device__ __forceinline__ float tanh_(float v) { return 2.0f * frcp(1.0f + __expf(-2.0f * v)) - 1.0f; }

__device__ __forceinline__ unsigned short f2bf(float f) {   // RNE float->bf16
    unsigned u = __float_as_uint(f);
    return (unsigned short)((u + 0x7fffu + ((u >> 16) & 1u)) >> 16);
}
#define BF(u) __uint_as_float(u)   // arg already shifted to high bits

#define DOT4(A, W, X0, X1, X2, X3) \
  { A = fmaf((X0), (W).x, A); A = fmaf((X1), (W).y, A); \
    A = fmaf((X2), (W).z, A); A = fmaf((X3), (W).w, A); }

#define ROW8A(P0,P1,P2,P3,P4,P5,P6,P7, IDX, X0,X1,X2,X3) { float4 w_; \
  w_ = P0[IDX]; DOT4(a0, w_, X0,X1,X2,X3) \
  w_ = P1[IDX]; DOT4(a1, w_, X0,X1,X2,X3) \
  w_ = P2[IDX]; DOT4(a2, w_, X0,X1,X2,X3) \
  w_ = P3[IDX]; DOT4(a3, w_, X0,X1,X2,X3) \
  w_ = P4[IDX]; DOT4(a4, w_, X0,X1,X2,X3) \
  w_ = P5[IDX]; DOT4(a5, w_, X0,X1,X2,X3) \
  w_ = P6[IDX]; DOT4(a6, w_, X0,X1,X2,X3) \
  w_ = P7[IDX]; DOT4(a7, w_, X0,X1,X2,X3) }

#define ROW8Z(P0,P1,P2,P3,P4,P5,P6,P7, IDX, X0,X1,X2,X3) { float4 w_; \
  w_ = P0[IDX]; DOT4(z0, w_, X0,X1,X2,X3) \
  w_ = P1[IDX]; DOT4(z1, w_, X0,X1,X2,X3) \
  w_ = P2[IDX]; DOT4(z2, w_, X0,X1,X2,X3) \
  w_ = P3[IDX]; DOT4(z3, w_, X0,X1,X2,X3) \
  w_ = P4[IDX]; DOT4(z4, w_, X0,X1,X2,X3) \
  w_ = P5[IDX]; DOT4(z5, w_, X0,X1,X2,X3) \
  w_ = P6[IDX]; DOT4(z6, w_, X0,X1,X2,X3) \
  w_ = P7[IDX]; DOT4(z7, w_, X0,X1,X2,X3) }

__global__ void __launch_bounds__(1024, 4)
lstm_fused(const float* __restrict__ x,
           const float* __restrict__ wih0, const float* __restrict__ whh0,
           const float* __restrict__ bih0, const float* __restrict__ bhh0,
           const float* __restrict__ wih1, const float* __restrict__ whh1,
           const float* __restrict__ bih1, const float* __restrict__ bhh1,
           float* __restrict__ out, float* __restrict__ red)
{
    __shared__ __align__(16) unsigned short xs[64 * 256]; // 32 KB bf16 x-tile (chunk-XOR swz)
    __shared__ __align__(16) float wl[20480];             // 80 KB: wih0|whh0|wih1|whh1
    __shared__ __align__(16) float h0s[2 * HB];           // 18 KB double-buffered h0
    __shared__ __align__(16) float h1s[HB];               // 9 KB h1 (in-place)

    const int tid  = threadIdx.x;
    const int lane = tid & 63;                                  // batch-local index
    const int wid  = __builtin_amdgcn_readfirstlane(tid >> 6);  // wave id (uniform)
    const int b0   = blockIdx.x << 6;

    // ---- stage weights to LDS (coalesced, once) ----
    for (int k = tid; k < 8192; k += 1024) wl[k]         = wih0[k];
    for (int k = tid; k < 4096; k += 1024) wl[8192 + k]  = whh0[k];
    for (int k = tid; k < 4096; k += 1024) wl[12288 + k] = wih1[k];
    for (int k = tid; k < 4096; k += 1024) wl[16384 + k] = whh1[k];
    for (int k = tid; k < 2 * HB; k += 1024) h0s[k] = 0.0f;
    for (int k = tid; k < HB;     k += 1024) h1s[k] = 0.0f;

    const int d0 = wid * 2, d1 = d0 + 1;

    // wave-uniform LDS row pointers
    const float4* wx0 = (const float4*)&wl[(d0      ) << 6];
    const float4* wx1 = (const float4*)&wl[(d1      ) << 6];
    const float4* wx2 = (const float4*)&wl[(32 + d0) << 6];
    const float4* wx3 = (const float4*)&wl[(32 + d1) << 6];
    const float4* wx4 = (const float4*)&wl[(64 + d0) << 6];
    const float4* wx5 = (const float4*)&wl[(64 + d1) << 6];
    const float4* wx6 = (const float4*)&wl[(96 + d0) << 6];
    const float4* wx7 = (const float4*)&wl[(96 + d1) << 6];
    const float4* wh0_ = (const float4*)&wl[8192 + ((d0      ) << 5)];
    const float4* wh1_ = (const float4*)&wl[8192 + ((d1      ) << 5)];
    const float4* wh2_ = (const float4*)&wl[8192 + ((32 + d0) << 5)];
    const float4* wh3_ = (const float4*)&wl[8192 + ((32 + d1) << 5)];
    const float4* wh4_ = (const float4*)&wl[8192 + ((64 + d0) << 5)];
    const float4* wh5_ = (const float4*)&wl[8192 + ((64 + d1) << 5)];
    const float4* wh6_ = (const float4*)&wl[8192 + ((96 + d0) << 5)];
    const float4* wh7_ = (const float4*)&wl[8192 + ((96 + d1) << 5)];
    const float4* wi0_ = (const float4*)&wl[12288 + ((d0      ) << 5)];
    const float4* wi1_ = (const float4*)&wl[12288 + ((d1      ) << 5)];
    const float4* wi2_ = (const float4*)&wl[12288 + ((32 + d0) << 5)];
    const float4* wi3_ = (const float4*)&wl[12288 + ((32 + d1) << 5)];
    const float4* wi4_ = (const float4*)&wl[12288 + ((64 + d0) << 5)];
    const float4* wi5_ = (const float4*)&wl[12288 + ((64 + d1) << 5)];
    const float4* wi6_ = (const float4*)&wl[12288 + ((96 + d0) << 5)];
    const float4* wi7_ = (const float4*)&wl[12288 + ((96 + d1) << 5)];
    const float4* wb0_ = (const float4*)&wl[16384 + ((d0      ) << 5)];
    const float4* wb1_ = (const float4*)&wl[16384 + ((d1      ) << 5)];
    const float4* wb2_ = (const float4*)&wl[16384 + ((32 + d0) << 5)];
    const float4* wb3_ = (const float4*)&wl[16384 + ((32 + d1) << 5)];
    const float4* wb4_ = (const float4*)&wl[16384 + ((64 + d0) << 5)];
    const float4* wb5_ = (const float4*)&wl[16384 + ((64 + d1) << 5)];
    const float4* wb6_ = (const float4*)&wl[16384 + ((96 + d0) << 5)];
    const float4* wb7_ = (const float4*)&wl[16384 + ((96 + d1) << 5)];

    // hoisted biases (wave-uniform -> SGPRs)
    const float bi0 = bih0[d0]      + bhh0[d0],      bi1 = bih0[d1]      + bhh0[d1];
    const float bf0 = bih0[32 + d0] + bhh0[32 + d0], bf1 = bih0[32 + d1] + bhh0[32 + d1];
    const float bg0 = bih0[64 + d0] + bhh0[64 + d0], bg1 = bih0[64 + d1] + bhh0[64 + d1];
    const float bo0 = bih0[96 + d0] + bhh0[96 + d0], bo1 = bih0[96 + d1] + bhh0[96 + d1];
    const float ci0 = bih1[d0]      + bhh1[d0],      ci1 = bih1[d1]      + bhh1[d1];
    const float cf0 = bih1[32 + d0] + bhh1[32 + d0], cf1 = bih1[32 + d1] + bhh1[32 + d1];
    const float cg0 = bih1[64 + d0] + bhh1[64 + d0], cg1 = bih1[64 + d1] + bhh1[64 + d1];
    const float co0 = bih1[96 + d0] + bhh1[96 + d0], co1 = bih1[96 + d1] + bhh1[96 + d1];

    __syncthreads();

    float c0a = 0.f, c0b = 0.f, c1a = 0.f, c1b = 0.f, vs = 0.f, vq = 0.f;
    int p = 0;

    const int xrow = lane << 8;     // bf16 elements per row = 256
    const int xsw  = lane & 31;     // read-side chunk XOR

    for (int t0 = 0; t0 < 64; t0 += 4) {
        // ---- stage x tile as bf16: x[b, i, t0..t0+3], 64 b x 64 i ----
        #pragma unroll
        for (int k = 0; k < 4; ++k) {
            const int bl = k * 16 + wid;
            const float4 v = *(const float4*)(x + (((size_t)(b0 + bl)) << 12) + (lane << 6) + t0);
            const int ib = lane >> 3, e = lane & 7;   // chunk-sub = i>>3, elem = i&7
            const int base = bl << 8;
            const int sw = bl & 31;
            xs[base + (((0  + ib) ^ sw) << 3) + e] = f2bf(v.x);
            xs[base + (((8  + ib) ^ sw) << 3) + e] = f2bf(v.y);
            xs[base + (((16 + ib) ^ sw) << 3) + e] = f2bf(v.z);
            xs[base + (((24 + ib) ^ sw) << 3) + e] = f2bf(v.w);
        }
        __syncthreads();

        #pragma unroll 1
        for (int tt = 0; tt < 4; ++tt) {
            const int t = t0 + tt;

            // ---------- layer 0 ----------
            float a0 = bi0, a1 = bi1, a2 = bf0, a3 = bf1;
            float a4 = bg0, a5 = bg1, a6 = bo0, a7 = bo1;

            #pragma unroll
            for (int cq = 0; cq < 8; ++cq) {
                const uint4 raw = *(const uint4*)&xs[xrow + ((((tt << 3) + cq) ^ xsw) << 3)];
                const float x0 = BF(raw.x << 16), x1 = BF(raw.x & 0xffff0000u);
                const float x2 = BF(raw.y << 16), x3 = BF(raw.y & 0xffff0000u);
                const float x4 = BF(raw.z << 16), x5 = BF(raw.z & 0xffff0000u);
                const float x6 = BF(raw.w << 16), x7 = BF(raw.w & 0xffff0000u);
                ROW8A(wx0,wx1,wx2,wx3,wx4,wx5,wx6,wx7, (cq << 1),     x0, x1, x2, x3)
                ROW8A(wx0,wx1,wx2,wx3,wx4,wx5,wx6,wx7, (cq << 1) + 1, x4, x5, x6, x7)
            }
            const float* h0r = &h0s[p * HB + lane * HS];
            #pragma unroll
            for (int j4 = 0; j4 < 8; ++j4) {
                const float4 hv = *(const float4*)&h0r[j4 << 2];
                ROW8A(wh0_,wh1_,wh2_,wh3_,wh4_,wh5_,wh6_,wh7_, j4, hv.x, hv.y, hv.z, hv.w)
            }
            const float si = sigf(a0), si2 = sigf(a1);
            const float sf = sigf(a2), sf2 = sigf(a3);
            const float tg = tanh_(a4), tg2 = tanh_(a5);
            const float so = sigf(a6), so2 = sigf(a7);
            c0a = sf  * c0a + si  * tg;   const float hn0 = so  * tanh_(c0a);
            c0b = sf2 * c0b + si2 * tg2;  const float hn1 = so2 * tanh_(c0b);
            float* h0w = &h0s[(p ^ 1) * HB + lane * HS];
            *(float2*)&h0w[d0] = make_float2(hn0, hn1);
            __syncthreads();   // h0-new visible to all waves

            // ---------- layer 1 ----------
            float z0 = ci0, z1 = ci1, z2 = cf0, z3 = cf1;
            float z4 = cg0, z5 = cg1, z6 = co0, z7 = co1;
            const float* h0n = &h0s[(p ^ 1) * HB + lane * HS];
            const float* h1r = &h1s[lane * HS];
            #pragma unroll
            for (int j4 = 0; j4 < 8; ++j4) {
                const float4 av = *(const float4*)&h0n[j4 << 2];
                const float4 bv = *(const float4*)&h1r[j4 << 2];
                ROW8Z(wi0_,wi1_,wi2_,wi3_,wi4_,wi5_,wi6_,wi7_, j4, av.x, av.y, av.z, av.w)
                ROW8Z(wb0_,wb1_,wb2_,wb3_,wb4_,wb5_,wb6_,wb7_, j4, bv.x, bv.y, bv.z, bv.w)
            }
            __syncthreads();   // all h1-old reads done before in-place write

            const float yi = sigf(z0), yi2 = sigf(z1);
            const float yf = sigf(z2), yf2 = sigf(z3);
            const float yg = tanh_(z4), yg2 = tanh_(z5);
            const float yo = sigf(z6), yo2 = sigf(z7);
            c1a = yf  * c1a + yi  * yg;   const float ho0 = yo  * tanh_(c1a);
            c1b = yf2 * c1b + yi2 * yg2;  const float ho1 = yo2 * tanh_(c1b);
            float* h1w = &h1s[lane * HS];
            *(float2*)&h1w[d0] = make_float2(ho0, ho1);

            *(float2*)(out + (((size_t)(b0 + lane)) << 11) + (t << 5) + d0) = make_float2(ho0, ho1);
            vs += ho0 + ho1;
            vq += ho0 * ho0 + ho1 * ho1;
            p ^= 1;
        }
    }

    // variance partials: wave reduce then one atomic pair per wave
    #pragma unroll
    for (int off = 32; off > 0; off >>= 1) {
        vs += __shfl_down(vs, off);
        vq += __shfl_down(vq, off);
    }
    if (lane == 0) {
        atomicAdd(&red[0], vs);
        atomicAdd(&red[1], vq);
    }
}

__global__ void zero_red(float* red)
{
    if (threadIdx.x < 2) red[threadIdx.x] = 0.0f;
}

__global__ void finalize(const float* __restrict__ red, float* __restrict__ out)
{
    const double N = 33554432.0;   // 16384*64*32
    const double s = (double)red[0];
    const double q = (double)red[1];
    const double var = (q - s * s / N) / (N - 1.0);
    const float score = 1.0f / (1.0f + __expf(-5.0f * (float)var));
    out[33554432] = score;
    out[33554433] = 1.0f - score;
}

extern "C" void kernel_launch(void* const* d_in, const int* in_sizes, int n_in,
                              void* d_out, int out_size, void* d_ws, size_t ws_size,
                              hipStream_t stream)
{
    const float* x    = (const float*)d_in[0];
    const float* wih0 = (const float*)d_in[1];
    const float* whh0 = (const float*)d_in[2];
    const float* bih0 = (const float*)d_in[3];
    const float* bhh0 = (const float*)d_in[4];
    const float* wih1 = (const float*)d_in[5];
    const float* whh1 = (const float*)d_in[6];
    const float* bih1 = (const float*)d_in[7];
    const float* bhh1 = (const float*)d_in[8];
    float* out = (float*)d_out;
    float* red = (float*)d_ws;   // red[0]=sum, red[1]=sumsq (ws is re-poisoned; zero first)

    hipLaunchKernelGGL(zero_red, dim3(1), dim3(64), 0, stream, red);
    hipLaunchKernelGGL(lstm_fused, dim3(256), dim3(1024), 0, stream,
                       x, wih0, whh0, bih0, bhh0, wih1, whh1, bih1, bhh1, out, red);
    hipLaunchKernelGGL(finalize, dim3(1), dim3(1), 0, stream, red, out);
}